// Round 1
// baseline (489.441 us; speedup 1.0000x reference)
//
#include <hip/hip_runtime.h>

#define BATCH 8192
#define FEAT  256
#define HID   256
#define NBINS 10
#define MULTV 21
#define MPAD  24
#define SCALE 0.0625f

// ws layout in floats
#define OFF_W0T 0
#define OFF_WBT 65536
#define OFF_WFT (5 * 65536)                    // 327680
#define OFF_H   (OFF_WFT + 256 * 256 * MPAD)   // 327680 + 1572864 = 1900544
#define WS_FLOATS (OFF_H + BATCH * HID)        // 3997696 floats ~= 16 MB

// ---------------------------------------------------------------------------
// prep: build transposed, mask-applied weights in workspace.
// mW0T[j*256+i]        = W0[i][j]            * (i%255 >= j)
// mWbT[k][j*256+i]     = Wb[k][i][j]         * (i%255 >= j%255)
// mWfT[j*6144+f*24+m]  = Wf[f*21+m][j]       * (f > j%255)      (m<21, else 0)
// ---------------------------------------------------------------------------
__global__ __launch_bounds__(256) void prep_kernel(
    const float* __restrict__ W0, const float* __restrict__ Wb,
    const float* __restrict__ Wf,
    float* __restrict__ mW0T, float* __restrict__ mWbT, float* __restrict__ mWfT)
{
    int idx = blockIdx.x * 256 + threadIdx.x;
    if (idx < 65536) {
        int j = idx >> 8, i = idx & 255;
        float v = W0[i * 256 + j];
        mW0T[idx] = ((i % 255) >= j) ? v : 0.f;
    } else if (idx < 5 * 65536) {
        int q = idx - 65536;
        int k = q >> 16, rem = q & 65535;
        int j = rem >> 8, i = rem & 255;
        float v = Wb[k * 65536 + i * 256 + j];
        mWbT[q] = ((i % 255) >= (j % 255)) ? v : 0.f;
    } else {
        int q = idx - 5 * 65536;
        if (q < 256 * 256 * MPAD) {
            int j = q / (256 * MPAD);
            int rem = q - j * (256 * MPAD);
            int ff = rem / MPAD;
            int m = rem - ff * MPAD;
            float v = 0.f;
            if (m < MULTV) {
                float wv = Wf[(ff * MULTV + m) * 256 + j];
                v = (ff > (j % 255)) ? wv : 0.f;
            }
            mWfT[q] = v;
        }
    }
}

// ---------------------------------------------------------------------------
// trunk: h = x@(W0m).T + b0; two pre-activation residual blocks; writes h.
// 32 rows per WG, 256 threads. Thread owns 4 rows (rq=t>>5) x 8 cols (c0).
// Activations staged transposed in LDS: T[buf][col 0..255][row 0..31 pad36].
// ---------------------------------------------------------------------------
__global__ __launch_bounds__(256) void trunk_kernel(
    const float* __restrict__ x, const float* __restrict__ ws,
    const float* __restrict__ b0, const float* __restrict__ bb,
    float* __restrict__ hbuf)
{
    __shared__ float T[2][256][36];
    const int t  = threadIdx.x;
    const int r0 = blockIdx.x * 32;
    const int c0 = (t & 31) * 8;
    const int rq = t >> 5;   // 0..7 -> rows rq*4 .. rq*4+3

    // stage x transposed: T[0][col][row]
    #pragma unroll
    for (int r = 0; r < 32; ++r)
        T[0][t][r] = x[(r0 + r) * 256 + t];
    __syncthreads();

    float h[4][8];
    float acc[4][8];

    auto gemm = [&](int sbuf, const float* __restrict__ W) {
        #pragma unroll
        for (int rr = 0; rr < 4; ++rr)
            #pragma unroll
            for (int k = 0; k < 8; ++k) acc[rr][k] = 0.f;
        for (int j = 0; j < 256; ++j) {
            float4 hv = *(const float4*)&T[sbuf][j][rq * 4];
            float4 wa = *(const float4*)&W[j * 256 + c0];
            float4 wb = *(const float4*)&W[j * 256 + c0 + 4];
            float hvv[4] = {hv.x, hv.y, hv.z, hv.w};
            float wv[8]  = {wa.x, wa.y, wa.z, wa.w, wb.x, wb.y, wb.z, wb.w};
            #pragma unroll
            for (int rr = 0; rr < 4; ++rr)
                #pragma unroll
                for (int k = 0; k < 8; ++k)
                    acc[rr][k] = __builtin_fmaf(hvv[rr], wv[k], acc[rr][k]);
        }
    };
    auto addbias = [&](const float* __restrict__ b) {
        float4 ba = *(const float4*)&b[c0];
        float4 bc = *(const float4*)&b[c0 + 4];
        float bv[8] = {ba.x, ba.y, ba.z, ba.w, bc.x, bc.y, bc.z, bc.w};
        #pragma unroll
        for (int rr = 0; rr < 4; ++rr)
            #pragma unroll
            for (int k = 0; k < 8; ++k) acc[rr][k] += bv[k];
    };
    auto store_relu_acc = [&](int dbuf) {
        #pragma unroll
        for (int k = 0; k < 8; ++k) {
            float4 q;
            q.x = fmaxf(acc[0][k], 0.f);
            q.y = fmaxf(acc[1][k], 0.f);
            q.z = fmaxf(acc[2][k], 0.f);
            q.w = fmaxf(acc[3][k], 0.f);
            *(float4*)&T[dbuf][c0 + k][rq * 4] = q;
        }
    };
    auto store_relu_h = [&](int dbuf) {
        #pragma unroll
        for (int k = 0; k < 8; ++k) {
            float4 q;
            q.x = fmaxf(h[0][k], 0.f);
            q.y = fmaxf(h[1][k], 0.f);
            q.z = fmaxf(h[2][k], 0.f);
            q.w = fmaxf(h[3][k], 0.f);
            *(float4*)&T[dbuf][c0 + k][rq * 4] = q;
        }
    };

    const float* mW0T = ws + OFF_W0T;
    const float* mWbT = ws + OFF_WBT;

    // L0: h = x@W0m.T + b0
    gemm(0, mW0T); addbias(b0);
    #pragma unroll
    for (int rr = 0; rr < 4; ++rr)
        #pragma unroll
        for (int k = 0; k < 8; ++k) h[rr][k] = acc[rr][k];
    store_relu_h(1);
    __syncthreads();
    // block 0
    gemm(1, mWbT + 0 * 65536); addbias(bb + 0 * 256);
    store_relu_acc(0);
    __syncthreads();
    gemm(0, mWbT + 1 * 65536); addbias(bb + 1 * 256);
    #pragma unroll
    for (int rr = 0; rr < 4; ++rr)
        #pragma unroll
        for (int k = 0; k < 8; ++k) h[rr][k] += acc[rr][k];
    store_relu_h(1);
    __syncthreads();
    // block 1
    gemm(1, mWbT + 2 * 65536); addbias(bb + 2 * 256);
    store_relu_acc(0);
    __syncthreads();
    gemm(0, mWbT + 3 * 65536); addbias(bb + 3 * 256);
    #pragma unroll
    for (int rr = 0; rr < 4; ++rr)
        #pragma unroll
        for (int k = 0; k < 8; ++k) h[rr][k] += acc[rr][k];

    // write h
    #pragma unroll
    for (int rr = 0; rr < 4; ++rr) {
        int base = (r0 + rq * 4 + rr) * 256 + c0;
        float4 q0 = make_float4(h[rr][0], h[rr][1], h[rr][2], h[rr][3]);
        float4 q1 = make_float4(h[rr][4], h[rr][5], h[rr][6], h[rr][7]);
        *(float4*)&hbuf[base]     = q0;
        *(float4*)&hbuf[base + 4] = q1;
    }
}

// ---------------------------------------------------------------------------
// head: params = h@Wfm.T + bf (triangular K), then quadratic spline.
// Grid (row tiles 256, feature tiles 8). 32 rows x 32 features per WG.
// Thread: fi = t&31 (feature), rq = t>>5 (4 rows), 4x21 accumulators.
// ---------------------------------------------------------------------------
__global__ __launch_bounds__(256) void head_kernel(
    const float* __restrict__ x, const float* __restrict__ wf,
    const float* __restrict__ hbuf, const float* __restrict__ bf,
    float* __restrict__ out, float* __restrict__ lad)
{
    __shared__ float Th[256][36];
    const int t     = threadIdx.x;
    const int r0    = blockIdx.x * 32;
    const int fbase = blockIdx.y * 32;
    const int fi = t & 31, rq = t >> 5;
    const int f  = fbase + fi;

    #pragma unroll
    for (int r = 0; r < 32; ++r)
        Th[t][r] = hbuf[(r0 + r) * 256 + t];
    __syncthreads();

    float acc[4][21];
    #pragma unroll
    for (int rr = 0; rr < 4; ++rr)
        #pragma unroll
        for (int m = 0; m < 21; ++m) acc[rr][m] = 0.f;

    const float* Wf0 = wf + f * MPAD;

    auto step = [&](int j) {
        float4 hv = *(const float4*)&Th[j][rq * 4];
        const float* wj = Wf0 + j * (256 * MPAD);
        float4 w0 = *(const float4*)(wj);
        float4 w1 = *(const float4*)(wj + 4);
        float4 w2 = *(const float4*)(wj + 8);
        float4 w3 = *(const float4*)(wj + 12);
        float4 w4 = *(const float4*)(wj + 16);
        float4 w5 = *(const float4*)(wj + 20);
        float wv[21] = {w0.x, w0.y, w0.z, w0.w, w1.x, w1.y, w1.z, w1.w,
                        w2.x, w2.y, w2.z, w2.w, w3.x, w3.y, w3.z, w3.w,
                        w4.x, w4.y, w4.z, w4.w, w5.x};
        float hvv[4] = {hv.x, hv.y, hv.z, hv.w};
        #pragma unroll
        for (int rr = 0; rr < 4; ++rr)
            #pragma unroll
            for (int m = 0; m < 21; ++m)
                acc[rr][m] = __builtin_fmaf(hvv[rr], wv[m], acc[rr][m]);
    };

    const int jmax = min(256, fbase + 32);
    for (int j = 0; j < jmax; ++j) step(j);
    if (jmax < 256) step(255);   // hid_deg(255)=1 is active for every f>=1

    float bfv[21];
    #pragma unroll
    for (int m = 0; m < 21; ++m) bfv[m] = bf[f * 21 + m];

    #pragma unroll
    for (int rr = 0; rr < 4; ++rr) {
        const int row = r0 + rq * 4 + rr;
        const float xv = x[row * 256 + f];
        float p[21];
        #pragma unroll
        for (int m = 0; m < 21; ++m) p[m] = (acc[rr][m] + bfv[m]) * SCALE;

        // widths = softmax(p[0..9])
        float wmax = p[0];
        #pragma unroll
        for (int i = 1; i < 10; ++i) wmax = fmaxf(wmax, p[i]);
        float ew[10]; float wsum = 0.f;
        #pragma unroll
        for (int i = 0; i < 10; ++i) { ew[i] = __expf(p[i] - wmax); wsum += ew[i]; }
        float winv = 1.0f / wsum;
        float wid[10];
        #pragma unroll
        for (int i = 0; i < 10; ++i) wid[i] = 1.0e-3f + 0.99f * ew[i] * winv;

        // heights
        float hx[11];
        #pragma unroll
        for (int i = 0; i < 11; ++i) hx[i] = __expf(p[10 + i]);
        float area = 0.f;
        #pragma unroll
        for (int i = 0; i < 10; ++i) area += 0.5f * (hx[i] + hx[i + 1]) * wid[i];
        float ainv = 1.0f / area;
        float hts[11];
        #pragma unroll
        for (int i = 0; i < 11; ++i) hts[i] = 1.0e-3f + 0.999f * hx[i] * ainv;

        // cdf / locs (padded, last forced to 1)
        float cdf[11], locs[11];
        cdf[0] = 0.f; locs[0] = 0.f;
        float ca = 0.f, la = 0.f;
        #pragma unroll
        for (int i = 0; i < 10; ++i) {
            ca += 0.5f * (hts[i] + hts[i + 1]) * wid[i];
            la += wid[i];
            cdf[i + 1]  = ca;
            locs[i + 1] = la;
        }
        cdf[10] = 1.0f; locs[10] = 1.0f;

        // searchsorted
        int cnt = 0;
        #pragma unroll
        for (int i = 0; i < 11; ++i) cnt += (xv >= locs[i]) ? 1 : 0;
        int idx = cnt - 1;
        idx = idx < 0 ? 0 : (idx > 9 ? 9 : idx);

        // compile-time-unrolled gather (keeps arrays in registers)
        float loc = 0.f, w = 0.f, lc = 0.f, hl = 0.f, hr = 0.f;
        #pragma unroll
        for (int i = 0; i < 10; ++i) {
            if (i == idx) { loc = locs[i]; w = wid[i]; lc = cdf[i]; hl = hts[i]; hr = hts[i + 1]; }
        }

        float aq = 0.5f * (hr - hl) * w;
        float bq = hl * w;
        float al = (xv - loc) / w;
        float y  = (aq * al + bq) * al + lc;
        y = fminf(fmaxf(y, 0.f), 1.f);
        out[row * 256 + f] = y;

        float lv = __logf(al * (hr - hl) + hl);
        // reduce over the 32 features held by this half-wave
        #pragma unroll
        for (int mm = 16; mm >= 1; mm >>= 1) lv += __shfl_xor(lv, mm);
        if (fi == 0) atomicAdd(&lad[row], lv);
    }
}

// ---------------------------------------------------------------------------
extern "C" void kernel_launch(void* const* d_in, const int* in_sizes, int n_in,
                              void* d_out, int out_size, void* d_ws, size_t ws_size,
                              hipStream_t stream)
{
    const float* x  = (const float*)d_in[0];
    const float* W0 = (const float*)d_in[1];
    const float* b0 = (const float*)d_in[2];
    const float* Wb = (const float*)d_in[3];
    const float* bb = (const float*)d_in[4];
    const float* Wf = (const float*)d_in[5];
    const float* bf = (const float*)d_in[6];

    float* out = (float*)d_out;
    float* lad = out + BATCH * FEAT;
    float* ws  = (float*)d_ws;

    // logabsdet accumulated via atomics -> zero it (d_out is poisoned each call)
    hipMemsetAsync(lad, 0, BATCH * sizeof(float), stream);

    // 65536*5 + 256*256*24 = 1900544 elements -> 7424 blocks of 256
    prep_kernel<<<7424, 256, 0, stream>>>(W0, Wb, Wf,
                                          ws + OFF_W0T, ws + OFF_WBT, ws + OFF_WFT);
    trunk_kernel<<<256, 256, 0, stream>>>(x, ws, b0, bb, ws + OFF_H);
    head_kernel<<<dim3(256, 8), 256, 0, stream>>>(x, ws + OFF_WFT, ws + OFF_H, bf,
                                                  out, lad);
}

// Round 2
// 259.681 us; speedup vs baseline: 1.8848x; 1.8848x over previous
//
#include <hip/hip_runtime.h>

typedef short bf16x8 __attribute__((ext_vector_type(8)));
typedef float f32x4  __attribute__((ext_vector_type(4)));

#define MFMA16(A,B,C) __builtin_amdgcn_mfma_f32_16x16x32_bf16(A,B,C,0,0,0)

// ws byte offsets
#define PTRUNK_OFF 0u          // 5 mats * 8ks * 16ct * 2pl * 64lane * 16B = 1.25 MB
#define PHEAD_OFF  1310720u    // 16bly * 8ks * 24ct * 2pl * 64lane * 16B = 6 MB
#define HHI_OFF    7602176u    // 8192*256 bf16 = 4 MB
#define HLO_OFF    11796480u   // 8192*256 bf16 = 4 MB  (total 15.25 MB)

__device__ __forceinline__ void split2(float v, short& hi, short& lo) {
    unsigned u = __float_as_uint(v);
    hi = (short)(u >> 16);                       // truncated bf16 hi
    float r = v - __uint_as_float(u & 0xffff0000u);
    lo = (short)(__float_as_uint(r) >> 16);      // bf16 of residual
}

// ---------------------------------------------------------------------------
// prep: pack masked weights into MFMA fragment order, split hi/lo bf16.
// Fragment element e of lane l: k = (l>>4)*8 + e, col = ct*16 + (l&15).
// trunk idx: mat*16384 + ((ks*16+ct)*2+pl)*64 + lane      (frag units of 16B)
// head  idx: (((bly*8+ks)*24+ct)*2+pl)*64 + lane
// ---------------------------------------------------------------------------
__global__ __launch_bounds__(256) void prep_kernel(
    const float* __restrict__ W0, const float* __restrict__ Wb,
    const float* __restrict__ Wf, unsigned char* __restrict__ wsb)
{
    const int b = blockIdx.x, t = threadIdx.x;
    if (b < 160) {                      // trunk: 5*8*16*64 = 40960 threads
        int id   = b * 256 + t;
        int lane = id & 63;
        int rest = id >> 6;             // mat*128 + ks*16 + ct
        int ct   = rest & 15;
        int ks   = (rest >> 4) & 7;
        int mat  = rest >> 7;           // 0..4
        int c    = ct * 16 + (lane & 15);
        int k0   = ks * 32 + (lane >> 4) * 8;
        const float* src = (mat == 0) ? (W0 + c * 256)
                                      : (Wb + (mat - 1) * 65536 + c * 256);
        int cd = c % 255;
        short hi[8], lo[8];
        #pragma unroll
        for (int e = 0; e < 8; ++e) {
            int k  = k0 + e;
            int kd = (mat == 0) ? k : (k % 255);
            float v = (cd >= kd) ? src[k] : 0.f;
            split2(v, hi[e], lo[e]);
        }
        bf16x8* base = (bf16x8*)(wsb + PTRUNK_OFF);
        int idx0 = mat * 16384 + ((ks * 16 + ct) * 2) * 64 + lane;
        base[idx0]      = *(bf16x8*)hi;
        base[idx0 + 64] = *(bf16x8*)lo;
    } else {                            // head: 16*8*24*64 = 196608 threads
        int id    = (b - 160) * 256 + t;
        int lane  = id & 63;
        int rest  = id >> 6;            // (bly*8+ks)*24 + ct
        int ct    = rest % 24;
        int rest2 = rest / 24;
        int ks    = rest2 & 7;
        int bly   = rest2 >> 3;
        int cl    = ct * 16 + (lane & 15);   // 0..383 within window
        int f     = bly * 16 + cl / 24;
        int m     = cl % 24;
        int k0    = ks * 32 + (lane >> 4) * 8;
        short hi[8], lo[8];
        #pragma unroll
        for (int e = 0; e < 8; ++e) {
            int k = k0 + e;
            float v = 0.f;
            if (m < 21) {
                int kd = k % 255;                     // k=255 -> 0
                if (f > kd) v = Wf[(f * 21 + m) * 256 + k];
            }
            split2(v, hi[e], lo[e]);
        }
        bf16x8* base = (bf16x8*)(wsb + PHEAD_OFF);
        int idx0 = (((bly * 8 + ks) * 24 + ct) * 2) * 64 + lane;
        base[idx0]      = *(bf16x8*)hi;
        base[idx0 + 64] = *(bf16x8*)lo;
    }
}

// ---------------------------------------------------------------------------
// trunk: 5 fused layers, 32 rows/WG (grid 256), 4 waves.
// wave w: row-tile rt=w&1 (16 rows), col-half ch=w>>1 (8 ctiles = 128 cols).
// Activations hi/lo bf16 in LDS [32][264]; residual h in f32 registers.
// ---------------------------------------------------------------------------
__global__ __launch_bounds__(256) void trunk_kernel(
    const float* __restrict__ x, unsigned char* __restrict__ wsb,
    const float* __restrict__ b0, const float* __restrict__ bb)
{
    __shared__ short a_hi[32][264];
    __shared__ short a_lo[32][264];
    const int t = threadIdx.x, lane = t & 63, w = t >> 6;
    const int rt = w & 1, ch = w >> 1;
    const int li = lane & 15, lg = lane >> 4;
    const int r0 = blockIdx.x * 32;

    // stage x -> hi/lo LDS
    {
        int row = t >> 3, c0 = (t & 7) * 32;
        const float* xr = x + (r0 + row) * 256 + c0;
        #pragma unroll
        for (int e = 0; e < 32; e += 8) {
            float4 va = *(const float4*)(xr + e);
            float4 vb = *(const float4*)(xr + e + 4);
            float v[8] = {va.x, va.y, va.z, va.w, vb.x, vb.y, vb.z, vb.w};
            short hi[8], lo[8];
            #pragma unroll
            for (int i = 0; i < 8; ++i) split2(v[i], hi[i], lo[i]);
            *(bf16x8*)&a_hi[row][c0 + e] = *(bf16x8*)hi;
            *(bf16x8*)&a_lo[row][c0 + e] = *(bf16x8*)lo;
        }
    }
    __syncthreads();

    const bf16x8* wp = (const bf16x8*)(wsb + PTRUNK_OFF);
    f32x4 hreg[8], acc[8];

    auto gemm = [&](int mat, const float* __restrict__ bias) {
        #pragma unroll
        for (int ci = 0; ci < 8; ++ci) acc[ci] = (f32x4){0.f, 0.f, 0.f, 0.f};
        const bf16x8* wm = wp + mat * 16384;
        for (int ks = 0; ks < 8; ++ks) {
            bf16x8 ah = *(const bf16x8*)&a_hi[rt * 16 + li][ks * 32 + lg * 8];
            bf16x8 al = *(const bf16x8*)&a_lo[rt * 16 + li][ks * 32 + lg * 8];
            #pragma unroll
            for (int ci = 0; ci < 8; ++ci) {
                int ctg = ch * 8 + ci;
                const bf16x8* bp = wm + ((ks * 16 + ctg) * 2) * 64 + lane;
                bf16x8 bh = bp[0];
                bf16x8 bl = bp[64];
                acc[ci] = MFMA16(ah, bh, acc[ci]);
                acc[ci] = MFMA16(ah, bl, acc[ci]);
                acc[ci] = MFMA16(al, bh, acc[ci]);
            }
        }
        #pragma unroll
        for (int ci = 0; ci < 8; ++ci) {
            float bv = bias[ch * 128 + ci * 16 + li];
            #pragma unroll
            for (int q = 0; q < 4; ++q) acc[ci][q] += bv;
        }
    };

    auto store_lds = [&](f32x4* s) {   // writes relu(s) as hi/lo
        #pragma unroll
        for (int ci = 0; ci < 8; ++ci)
            #pragma unroll
            for (int q = 0; q < 4; ++q) {
                float v = fmaxf(s[ci][q], 0.f);
                short hi, lo; split2(v, hi, lo);
                int row = rt * 16 + lg * 4 + q;
                int col = ch * 128 + ci * 16 + li;
                a_hi[row][col] = hi;
                a_lo[row][col] = lo;
            }
    };

    // L0
    gemm(0, b0);
    #pragma unroll
    for (int ci = 0; ci < 8; ++ci) hreg[ci] = acc[ci];
    __syncthreads(); store_lds(acc); __syncthreads();
    // block 0
    gemm(1, bb + 0);
    __syncthreads(); store_lds(acc); __syncthreads();
    gemm(2, bb + 256);
    #pragma unroll
    for (int ci = 0; ci < 8; ++ci) hreg[ci] += acc[ci];
    __syncthreads(); store_lds(hreg); __syncthreads();
    // block 1
    gemm(3, bb + 512);
    __syncthreads(); store_lds(acc); __syncthreads();
    gemm(4, bb + 768);
    #pragma unroll
    for (int ci = 0; ci < 8; ++ci) hreg[ci] += acc[ci];

    // write final h (no relu) hi/lo to global
    short* ghi = (short*)(wsb + HHI_OFF);
    short* glo = (short*)(wsb + HLO_OFF);
    #pragma unroll
    for (int ci = 0; ci < 8; ++ci)
        #pragma unroll
        for (int q = 0; q < 4; ++q) {
            short hi, lo; split2(hreg[ci][q], hi, lo);
            int row = r0 + rt * 16 + lg * 4 + q;
            int col = ch * 128 + ci * 16 + li;
            ghi[row * 256 + col] = hi;
            glo[row * 256 + col] = lo;
        }
}

// ---------------------------------------------------------------------------
// head: 16 rows x 16 features (384 padded param cols = 24 ctiles) per WG.
// grid (512, 16). 4 waves x 6 ctiles. Triangular kstep set + kstep 7 (j=255).
// Params redistributed through LDS, spline fused, 1 (row,feature) per thread.
// ---------------------------------------------------------------------------
__global__ __launch_bounds__(256) void head_kernel(
    const float* __restrict__ x, unsigned char* __restrict__ wsb,
    const float* __restrict__ bfp, float* __restrict__ out,
    float* __restrict__ lad)
{
    __shared__ short a_hi[16][264];
    __shared__ short a_lo[16][264];
    __shared__ float prm[16][400];   // [row][f_local*25 + m]
    const int t = threadIdx.x, lane = t & 63, w = t >> 6;
    const int li = lane & 15, lg = lane >> 4;
    const int r0  = blockIdx.x * 16;
    const int bly = blockIdx.y;

    // stage h hi/lo
    {
        const bf16x8* shi = (const bf16x8*)(wsb + HHI_OFF) + (size_t)blockIdx.x * 512 + t * 2;
        const bf16x8* slo = (const bf16x8*)(wsb + HLO_OFF) + (size_t)blockIdx.x * 512 + t * 2;
        int row = t >> 4, col = (t & 15) * 16;
        *(bf16x8*)&a_hi[row][col]     = shi[0];
        *(bf16x8*)&a_hi[row][col + 8] = shi[1];
        *(bf16x8*)&a_lo[row][col]     = slo[0];
        *(bf16x8*)&a_lo[row][col + 8] = slo[1];
    }
    __syncthreads();

    f32x4 acc[6];
    #pragma unroll
    for (int ci = 0; ci < 6; ++ci) acc[ci] = (f32x4){0.f, 0.f, 0.f, 0.f};

    const bf16x8* wh = (const bf16x8*)(wsb + PHEAD_OFF);
    const int fmax = bly * 16 + 15;
    int nk = (fmax + 31) >> 5;               // ceil(fmax/32), 1..8
    const int nloop = nk + (nk < 8 ? 1 : 0); // append kstep 7 (j=255 col)

    for (int s = 0; s < nloop; ++s) {
        int ks = (s < nk) ? s : 7;
        bf16x8 ah = *(const bf16x8*)&a_hi[li][ks * 32 + lg * 8];
        bf16x8 al = *(const bf16x8*)&a_lo[li][ks * 32 + lg * 8];
        #pragma unroll
        for (int ci = 0; ci < 6; ++ci) {
            int ct = w * 6 + ci;
            const bf16x8* bp = wh + (((bly * 8 + ks) * 24 + ct) * 2) * 64 + lane;
            bf16x8 bh = bp[0];
            bf16x8 bl = bp[64];
            acc[ci] = MFMA16(ah, bh, acc[ci]);
            acc[ci] = MFMA16(ah, bl, acc[ci]);
            acc[ci] = MFMA16(al, bh, acc[ci]);
        }
    }

    // scatter C fragments to param LDS
    #pragma unroll
    for (int ci = 0; ci < 6; ++ci) {
        int cl = (w * 6 + ci) * 16 + li;     // 0..383
        int fl = cl / 24, m = cl % 24;
        #pragma unroll
        for (int q = 0; q < 4; ++q)
            prm[lg * 4 + q][fl * 25 + m] = acc[ci][q];
    }
    __syncthreads();

    // spline: one (row, feature) per thread
    {
        const int row = t >> 4, fl = t & 15;
        const int f = bly * 16 + fl;
        const int grow = r0 + row;
        const float xv = x[grow * 256 + f];
        const float* bq = bfp + f * 21;
        float p[21];
        #pragma unroll
        for (int m = 0; m < 21; ++m)
            p[m] = (prm[row][fl * 25 + m] + bq[m]) * 0.0625f;

        float wmax = p[0];
        #pragma unroll
        for (int i = 1; i < 10; ++i) wmax = fmaxf(wmax, p[i]);
        float ew[10]; float wsum = 0.f;
        #pragma unroll
        for (int i = 0; i < 10; ++i) { ew[i] = __expf(p[i] - wmax); wsum += ew[i]; }
        float winv = 1.0f / wsum;
        float wid[10];
        #pragma unroll
        for (int i = 0; i < 10; ++i) wid[i] = 1.0e-3f + 0.99f * ew[i] * winv;

        float hx[11];
        #pragma unroll
        for (int i = 0; i < 11; ++i) hx[i] = __expf(p[10 + i]);
        float area = 0.f;
        #pragma unroll
        for (int i = 0; i < 10; ++i) area += 0.5f * (hx[i] + hx[i + 1]) * wid[i];
        float ainv = 1.0f / area;
        float hts[11];
        #pragma unroll
        for (int i = 0; i < 11; ++i) hts[i] = 1.0e-3f + 0.999f * hx[i] * ainv;

        float cdf[11], locs[11];
        cdf[0] = 0.f; locs[0] = 0.f;
        float ca = 0.f, la = 0.f;
        #pragma unroll
        for (int i = 0; i < 10; ++i) {
            ca += 0.5f * (hts[i] + hts[i + 1]) * wid[i];
            la += wid[i];
            cdf[i + 1] = ca; locs[i + 1] = la;
        }
        cdf[10] = 1.0f; locs[10] = 1.0f;

        int cnt = 0;
        #pragma unroll
        for (int i = 0; i < 11; ++i) cnt += (xv >= locs[i]) ? 1 : 0;
        int idx = cnt - 1;
        idx = idx < 0 ? 0 : (idx > 9 ? 9 : idx);

        float loc = 0.f, ww = 0.f, lc = 0.f, hl = 0.f, hr = 0.f;
        #pragma unroll
        for (int i = 0; i < 10; ++i)
            if (i == idx) { loc = locs[i]; ww = wid[i]; lc = cdf[i]; hl = hts[i]; hr = hts[i + 1]; }

        float aq = 0.5f * (hr - hl) * ww;
        float bq2 = hl * ww;
        float al2 = (xv - loc) / ww;
        float y = (aq * al2 + bq2) * al2 + lc;
        y = fminf(fmaxf(y, 0.f), 1.f);
        out[grow * 256 + f] = y;

        float lv = __logf(al2 * (hr - hl) + hl);
        #pragma unroll
        for (int mm = 1; mm <= 8; mm <<= 1) lv += __shfl_xor(lv, mm);
        if ((t & 15) == 0) atomicAdd(&lad[grow], lv);
    }
}

// ---------------------------------------------------------------------------
extern "C" void kernel_launch(void* const* d_in, const int* in_sizes, int n_in,
                              void* d_out, int out_size, void* d_ws, size_t ws_size,
                              hipStream_t stream)
{
    const float* x  = (const float*)d_in[0];
    const float* W0 = (const float*)d_in[1];
    const float* b0 = (const float*)d_in[2];
    const float* Wb = (const float*)d_in[3];
    const float* bb = (const float*)d_in[4];
    const float* Wf = (const float*)d_in[5];
    const float* bf = (const float*)d_in[6];

    float* out = (float*)d_out;
    float* lad = out + 8192 * 256;
    unsigned char* wsb = (unsigned char*)d_ws;

    hipMemsetAsync(lad, 0, 8192 * sizeof(float), stream);

    prep_kernel<<<928, 256, 0, stream>>>(W0, Wb, Wf, wsb);
    trunk_kernel<<<256, 256, 0, stream>>>(x, wsb, b0, bb);
    head_kernel<<<dim3(512, 16), 256, 0, stream>>>(x, wsb, bf, out, lad);
}

// Round 3
// 171.855 us; speedup vs baseline: 2.8480x; 1.5111x over previous
//
#include <hip/hip_runtime.h>

typedef _Float16 f16;
typedef f16 f16x8 __attribute__((ext_vector_type(8)));
typedef float f32x4 __attribute__((ext_vector_type(4)));

#define MFMA(A,B,C) __builtin_amdgcn_mfma_f32_16x16x32_f16(A,B,C,0,0,0)

// ws byte offsets (total 3.4 MB -> whole weight set is L2-resident per XCD)
#define PTRUNK 0u          // 5 mats * 8ks * 16ct * 64lane * 16B = 640 KB
#define PHEAD  655360u     // 16bly * 8ks * 21ct * 64lane * 16B = 2.625 MB

__device__ __forceinline__ void fsplit(float v, f16& hi, f16& lo) {
    hi = (f16)v;
    lo = (f16)(v - (float)hi);
}

// ---------------------------------------------------------------------------
// prep: pack masked weights into MFMA fragment order, single fp16.
// Fragment element e of lane l: k = (l>>4)*8+e, col = ct*16+(l&15).
// Head K is ROTATED: kpos=0 -> j=255, kpos>=1 -> j=kpos-1  (prefix K-sets).
// ---------------------------------------------------------------------------
__global__ __launch_bounds__(256) void prep_kernel(
    const float* __restrict__ W0, const float* __restrict__ Wb,
    const float* __restrict__ Wf, unsigned char* __restrict__ wsb)
{
    const int id   = blockIdx.x * 256 + threadIdx.x;
    const int lane = id & 63;
    const int frag = id >> 6;
    const int li = lane & 15, lg = lane >> 4;
    if (frag < 640) {                    // trunk: frag = mat*128 + ks*16 + ct
        int ct = frag & 15, ks = (frag >> 4) & 7, mat = frag >> 7;
        int c  = ct * 16 + li;
        int k0 = ks * 32 + lg * 8;
        const float* src = (mat == 0) ? (W0 + c * 256)
                                      : (Wb + (mat - 1) * 65536 + c * 256);
        int cd = c % 255;
        f16 v[8];
        #pragma unroll
        for (int e = 0; e < 8; ++e) {
            int k = k0 + e;
            bool act = (mat == 0) ? (cd >= k) : (cd >= (k % 255));
            v[e] = act ? (f16)src[k] : (f16)0.f;
        }
        ((f16x8*)(wsb + PTRUNK))[frag * 64 + lane] = *(f16x8*)v;
    } else {                             // head: hfrag = (bly*8+ks)*21 + ct
        int hfrag = frag - 640;          // 0..2687
        int ct  = hfrag % 21;
        int tmp = hfrag / 21;
        int ks  = tmp & 7;
        int bly = tmp >> 3;
        int cl  = ct * 16 + li;          // 0..335
        int f   = bly * 16 + cl / 21;
        int m   = cl % 21;
        int k0  = ks * 32 + lg * 8;
        f16 v[8];
        #pragma unroll
        for (int e = 0; e < 8; ++e) {
            int k = k0 + e;
            int j = (k == 0) ? 255 : (k - 1);   // rotation
            int jd = j % 255;
            float wv = (f > jd) ? Wf[(f * 21 + m) * 256 + j] : 0.f;
            v[e] = (f16)wv;
        }
        ((f16x8*)(wsb + PHEAD))[hfrag * 64 + lane] = *(f16x8*)v;
    }
}

// ---------------------------------------------------------------------------
// mega: trunk (5 fused masked GEMM layers) + head (all 16 f-blocks) + spline.
// 512 WGs x 256 thr, 16 rows/WG, 2 WGs/CU. Wave w owns 64 trunk cols /
// ~5 head ctiles. Activations fp16 hi/lo in double-buffered LDS; final h
// stored K-rotated for the head. logabsdet accumulated in registers.
// ---------------------------------------------------------------------------
__global__ __launch_bounds__(256, 2) void mega_kernel(
    const float* __restrict__ x, const unsigned char* __restrict__ wsb,
    const float* __restrict__ b0, const float* __restrict__ bb,
    const float* __restrict__ bfp, float* __restrict__ out,
    float* __restrict__ lad)
{
    __shared__ f16 Ah[2][16][264];
    __shared__ f16 Al[2][16][264];
    __shared__ float prm[16][353];

    const int t = threadIdx.x, lane = t & 63, w = t >> 6;
    const int li = lane & 15, lg = lane >> 4;
    const int r0 = blockIdx.x * 16;

    // ---- stage x (unrotated) ----
    {
        int row = t >> 4, cb = (t & 15) * 16;
        const float* xr = x + (r0 + row) * 256 + cb;
        f16 hi[16], lo[16];
        #pragma unroll
        for (int j = 0; j < 16; j += 4) {
            float4 v4 = *(const float4*)(xr + j);
            fsplit(v4.x, hi[j],     lo[j]);
            fsplit(v4.y, hi[j + 1], lo[j + 1]);
            fsplit(v4.z, hi[j + 2], lo[j + 2]);
            fsplit(v4.w, hi[j + 3], lo[j + 3]);
        }
        *(f16x8*)&Ah[0][row][cb]     = *(f16x8*)&hi[0];
        *(f16x8*)&Ah[0][row][cb + 8] = *(f16x8*)&hi[8];
        *(f16x8*)&Al[0][row][cb]     = *(f16x8*)&lo[0];
        *(f16x8*)&Al[0][row][cb + 8] = *(f16x8*)&lo[8];
    }
    __syncthreads();

    const f16x8* wt = (const f16x8*)(wsb + PTRUNK);
    const f16x8* wh = (const f16x8*)(wsb + PHEAD);

    f32x4 h[4], acc[4];
    const int nkp = 2 * w + 2;   // prefix K-steps this wave needs

    auto gemm = [&](int mat, int src, int add7, const float* __restrict__ bias) {
        #pragma unroll
        for (int ci = 0; ci < 4; ++ci) acc[ci] = (f32x4){0.f, 0.f, 0.f, 0.f};
        const f16x8* wm = wt + mat * 8192;
        const int tot = nkp + add7;
        for (int s = 0; s < tot; ++s) {
            int ks = (s < nkp) ? s : 7;
            f16x8 ah = *(const f16x8*)&Ah[src][li][ks * 32 + lg * 8];
            f16x8 al = *(const f16x8*)&Al[src][li][ks * 32 + lg * 8];
            #pragma unroll
            for (int ci = 0; ci < 4; ++ci) {
                f16x8 bv = wm[(ks * 16 + (w * 4 + ci)) * 64 + lane];
                acc[ci] = MFMA(ah, bv, acc[ci]);
                acc[ci] = MFMA(al, bv, acc[ci]);
            }
        }
        #pragma unroll
        for (int ci = 0; ci < 4; ++ci) {
            float bv = bias[(w * 4 + ci) * 16 + li];
            #pragma unroll
            for (int q = 0; q < 4; ++q) acc[ci][q] += bv;
        }
    };

    auto store_act = [&](int dst, f32x4* s, bool relu, bool rot) {
        #pragma unroll
        for (int ci = 0; ci < 4; ++ci) {
            int c  = (w * 4 + ci) * 16 + li;
            int cc = rot ? ((c + 1) & 255) : c;
            #pragma unroll
            for (int q = 0; q < 4; ++q) {
                float v = s[ci][q];
                if (relu) v = fmaxf(v, 0.f);
                f16 hi, lo; fsplit(v, hi, lo);
                Ah[dst][lg * 4 + q][cc] = hi;
                Al[dst][lg * 4 + q][cc] = lo;
            }
        }
    };

    // ---- trunk ----
    gemm(0, 0, 0, b0);
    #pragma unroll
    for (int ci = 0; ci < 4; ++ci) h[ci] = acc[ci];
    store_act(1, acc, true, false);
    __syncthreads();

    gemm(1, 1, (w < 3) ? 1 : 0, bb + 0);
    store_act(0, acc, true, false);
    __syncthreads();

    gemm(2, 0, (w < 3) ? 1 : 0, bb + 256);
    #pragma unroll
    for (int ci = 0; ci < 4; ++ci) h[ci] += acc[ci];
    store_act(1, h, true, false);
    __syncthreads();

    gemm(3, 1, (w < 3) ? 1 : 0, bb + 512);
    store_act(0, acc, true, false);
    __syncthreads();

    gemm(4, 0, (w < 3) ? 1 : 0, bb + 768);
    #pragma unroll
    for (int ci = 0; ci < 4; ++ci) h[ci] += acc[ci];
    store_act(1, h, false, true);        // final h: no relu, K-rotated
    __syncthreads();

    // ---- head + spline ----
    const int ct0 = (w == 0) ? 0 : (5 * w + 1);
    const int cnt = (w == 0) ? 6 : 5;
    const int srow = t >> 4, sfl = t & 15;
    float ladreg = 0.f;

    for (int bly = 0; bly < 16; ++bly) {
        const int nloop = (bly + 2) >> 1;     // ceil((bly+1)/2)
        f32x4 hacc[6];
        #pragma unroll
        for (int ci = 0; ci < 6; ++ci) hacc[ci] = (f32x4){0.f, 0.f, 0.f, 0.f};

        for (int s = 0; s < nloop; ++s) {
            f16x8 ah = *(const f16x8*)&Ah[1][li][s * 32 + lg * 8];
            f16x8 al = *(const f16x8*)&Al[1][li][s * 32 + lg * 8];
            #pragma unroll
            for (int ci = 0; ci < 6; ++ci) {
                if (ci < cnt) {
                    f16x8 bv = wh[((bly * 8 + s) * 21 + ct0 + ci) * 64 + lane];
                    hacc[ci] = MFMA(ah, bv, hacc[ci]);
                    hacc[ci] = MFMA(al, bv, hacc[ci]);
                }
            }
        }

        // scatter C fragments -> param LDS
        #pragma unroll
        for (int ci = 0; ci < 6; ++ci) {
            if (ci < cnt) {
                int cl = (ct0 + ci) * 16 + li;
                int fl = cl / 21, m = cl - fl * 21;
                #pragma unroll
                for (int q = 0; q < 4; ++q)
                    prm[lg * 4 + q][fl * 22 + m] = hacc[ci][q];
            }
        }
        __syncthreads();

        // spline: one (row, feature) per thread
        {
            const int f = bly * 16 + sfl;
            const int grow = r0 + srow;
            const float xv = x[grow * 256 + f];
            const float* bq = bfp + f * 21;
            float p[21];
            #pragma unroll
            for (int m = 0; m < 21; ++m)
                p[m] = (prm[srow][sfl * 22 + m] + bq[m]) * 0.0625f;

            float wmax = p[0];
            #pragma unroll
            for (int i = 1; i < 10; ++i) wmax = fmaxf(wmax, p[i]);
            float ew[10]; float wsum = 0.f;
            #pragma unroll
            for (int i = 0; i < 10; ++i) { ew[i] = __expf(p[i] - wmax); wsum += ew[i]; }
            float winv = 1.0f / wsum;
            float wid[10];
            #pragma unroll
            for (int i = 0; i < 10; ++i) wid[i] = 1.0e-3f + 0.99f * ew[i] * winv;

            float hx[11];
            #pragma unroll
            for (int i = 0; i < 11; ++i) hx[i] = __expf(p[10 + i]);
            float area = 0.f;
            #pragma unroll
            for (int i = 0; i < 10; ++i) area += 0.5f * (hx[i] + hx[i + 1]) * wid[i];
            float ainv = 1.0f / area;
            float hts[11];
            #pragma unroll
            for (int i = 0; i < 11; ++i) hts[i] = 1.0e-3f + 0.999f * hx[i] * ainv;

            float cdf[11], locs[11];
            cdf[0] = 0.f; locs[0] = 0.f;
            float ca = 0.f, la = 0.f;
            #pragma unroll
            for (int i = 0; i < 10; ++i) {
                ca += 0.5f * (hts[i] + hts[i + 1]) * wid[i];
                la += wid[i];
                cdf[i + 1] = ca; locs[i + 1] = la;
            }
            cdf[10] = 1.0f; locs[10] = 1.0f;

            int cntk = 0;
            #pragma unroll
            for (int i = 0; i < 11; ++i) cntk += (xv >= locs[i]) ? 1 : 0;
            int idx = cntk - 1;
            idx = idx < 0 ? 0 : (idx > 9 ? 9 : idx);

            float loc = 0.f, ww = 0.f, lc = 0.f, hl = 0.f, hr = 0.f;
            #pragma unroll
            for (int i = 0; i < 10; ++i)
                if (i == idx) { loc = locs[i]; ww = wid[i]; lc = cdf[i]; hl = hts[i]; hr = hts[i + 1]; }

            float aq  = 0.5f * (hr - hl) * ww;
            float bq2 = hl * ww;
            float al2 = (xv - loc) / ww;
            float y = (aq * al2 + bq2) * al2 + lc;
            y = fminf(fmaxf(y, 0.f), 1.f);
            out[grow * 256 + f] = y;

            ladreg += __logf(al2 * (hr - hl) + hl);
        }
        __syncthreads();
    }

    // ---- logabsdet: reduce over the 16 features this thread-group covers ----
    float s = ladreg;
    #pragma unroll
    for (int mm = 1; mm <= 8; mm <<= 1) s += __shfl_xor(s, mm);
    if (sfl == 0) lad[r0 + srow] = s;
}

// ---------------------------------------------------------------------------
extern "C" void kernel_launch(void* const* d_in, const int* in_sizes, int n_in,
                              void* d_out, int out_size, void* d_ws, size_t ws_size,
                              hipStream_t stream)
{
    const float* x  = (const float*)d_in[0];
    const float* W0 = (const float*)d_in[1];
    const float* b0 = (const float*)d_in[2];
    const float* Wb = (const float*)d_in[3];
    const float* bb = (const float*)d_in[4];
    const float* Wf = (const float*)d_in[5];
    const float* bf = (const float*)d_in[6];

    float* out = (float*)d_out;
    float* lad = out + 8192 * 256;
    unsigned char* wsb = (unsigned char*)d_ws;

    // (640 + 2688) frags * 64 lanes = 212992 threads -> 832 WGs
    prep_kernel<<<832, 256, 0, stream>>>(W0, Wb, Wf, wsb);
    mega_kernel<<<512, 256, 0, stream>>>(x, wsb, b0, bb, bf, out, lad);
}

// Round 4
// 162.164 us; speedup vs baseline: 3.0182x; 1.0598x over previous
//
#include <hip/hip_runtime.h>

typedef _Float16 f16;
typedef f16 f16x8 __attribute__((ext_vector_type(8)));
typedef float f32x4 __attribute__((ext_vector_type(4)));

#define MFMA(A,B,C) __builtin_amdgcn_mfma_f32_16x16x32_f16(A,B,C,0,0,0)

// ws byte offsets (3.4 MB total -> L2-resident)
#define PTRUNK 0u          // 5 mats * 8ks * 16ct * 64lane * 16B = 640 KB
#define PHEAD  655360u     // 16bly * 8ks * 21ct * 64lane * 16B = 2.625 MB

__device__ __forceinline__ void fsplit(float v, f16& hi, f16& lo) {
    hi = (f16)v;
    lo = (f16)(v - (float)hi);
}

// ---------------------------------------------------------------------------
// prep: pack masked weights into MFMA fragment order, single fp16.
// Fragment element e of lane l: k = (l>>4)*8+e, col = ct*16+(l&15).
// Head K is ROTATED: kpos=0 -> j=255, kpos>=1 -> j=kpos-1 (prefix K-sets).
// ---------------------------------------------------------------------------
__global__ __launch_bounds__(256) void prep_kernel(
    const float* __restrict__ W0, const float* __restrict__ Wb,
    const float* __restrict__ Wf, unsigned char* __restrict__ wsb)
{
    const int id   = blockIdx.x * 256 + threadIdx.x;
    const int lane = id & 63;
    const int frag = id >> 6;
    const int li = lane & 15, lg = lane >> 4;
    if (frag < 640) {                    // trunk: frag = mat*128 + ks*16 + ct
        int ct = frag & 15, ks = (frag >> 4) & 7, mat = frag >> 7;
        int c  = ct * 16 + li;
        int k0 = ks * 32 + lg * 8;
        const float* src = (mat == 0) ? (W0 + c * 256)
                                      : (Wb + (mat - 1) * 65536 + c * 256);
        int cd = c % 255;
        f16 v[8];
        #pragma unroll
        for (int e = 0; e < 8; ++e) {
            int k = k0 + e;
            bool act = (mat == 0) ? (cd >= k) : (cd >= (k % 255));
            v[e] = act ? (f16)src[k] : (f16)0.f;
        }
        ((f16x8*)(wsb + PTRUNK))[frag * 64 + lane] = *(f16x8*)v;
    } else {                             // head: hfrag = (bly*8+ks)*21 + ct
        int hfrag = frag - 640;          // 0..2687
        int ct  = hfrag % 21;
        int tmp = hfrag / 21;
        int ks  = tmp & 7;
        int bly = tmp >> 3;
        int cl  = ct * 16 + li;          // 0..335 within window
        int f   = bly * 16 + cl / 21;
        int m   = cl % 21;
        int k0  = ks * 32 + lg * 8;
        f16 v[8];
        #pragma unroll
        for (int e = 0; e < 8; ++e) {
            int k = k0 + e;
            int j = (k == 0) ? 255 : (k - 1);   // rotation
            int jd = j % 255;
            float wv = (f > jd) ? Wf[(f * 21 + m) * 256 + j] : 0.f;
            v[e] = (f16)wv;
        }
        ((f16x8*)(wsb + PHEAD))[hfrag * 64 + lane] = *(f16x8*)v;
    }
}

// ---------------------------------------------------------------------------
// mega: trunk (5 masked GEMM layers, 1 barrier each) + barrier-free head.
// 512 WGs x 256 thr, 16 rows/WG, 2 WGs/CU. Head: wave w privately owns
// bly {w, w+4, w+8, w+12} (balanced), 4 passes of 4 features each; scatter
// and spline are wave-local (lgkmcnt fences, no __syncthreads).
// ---------------------------------------------------------------------------
__global__ __launch_bounds__(256, 2) void mega_kernel(
    const float* __restrict__ x, const unsigned char* __restrict__ wsb,
    const float* __restrict__ b0, const float* __restrict__ bb,
    const float* __restrict__ bfp, float* __restrict__ out,
    float* __restrict__ lad)
{
    __shared__ f16  Ah[2][16][280];
    __shared__ f16  Al[2][16][280];
    __shared__ float prm[4][16][100];
    __shared__ float ladp[4][16];

    const int t = threadIdx.x, lane = t & 63;
    const int wu = __builtin_amdgcn_readfirstlane(t >> 6);   // wave id, scalar
    const int li = lane & 15, lg = lane >> 4;
    const int r0 = blockIdx.x * 16;

    // ---- stage x hi/lo ----
    {
        int row = t >> 4, cb = (t & 15) * 16;
        const float* xr = x + (r0 + row) * 256 + cb;
        f16 hi[16], lo[16];
        #pragma unroll
        for (int j = 0; j < 16; j += 4) {
            float4 v4 = *(const float4*)(xr + j);
            fsplit(v4.x, hi[j],     lo[j]);
            fsplit(v4.y, hi[j + 1], lo[j + 1]);
            fsplit(v4.z, hi[j + 2], lo[j + 2]);
            fsplit(v4.w, hi[j + 3], lo[j + 3]);
        }
        *(f16x8*)&Ah[0][row][cb]     = *(f16x8*)&hi[0];
        *(f16x8*)&Ah[0][row][cb + 8] = *(f16x8*)&hi[8];
        *(f16x8*)&Al[0][row][cb]     = *(f16x8*)&lo[0];
        *(f16x8*)&Al[0][row][cb + 8] = *(f16x8*)&lo[8];
    }
    __syncthreads();

    const f16x8* wt = (const f16x8*)(wsb + PTRUNK);
    const f16x8* wh = (const f16x8*)(wsb + PHEAD);

    f32x4 h[4], acc[4];
    const int nkp = 2 * wu + 2;

    auto gemm = [&](int mat, int src, int add7, const float* __restrict__ bias) {
        #pragma unroll
        for (int ci = 0; ci < 4; ++ci) acc[ci] = (f32x4){0.f, 0.f, 0.f, 0.f};
        #pragma unroll
        for (int ks = 0; ks < 8; ++ks) {
            if (ks < nkp || (add7 && ks == 7)) {        // wave-uniform branch
                f16x8 ah = *(const f16x8*)&Ah[src][li][ks * 32 + lg * 8];
                f16x8 al = *(const f16x8*)&Al[src][li][ks * 32 + lg * 8];
                #pragma unroll
                for (int ci = 0; ci < 4; ++ci) {
                    f16x8 bv = wt[mat * 8192 + (ks * 16 + wu * 4 + ci) * 64 + lane];
                    acc[ci] = MFMA(al, bv, acc[ci]);
                    acc[ci] = MFMA(ah, bv, acc[ci]);
                }
            }
        }
        #pragma unroll
        for (int ci = 0; ci < 4; ++ci) {
            float bv = bias[(wu * 4 + ci) * 16 + li];
            #pragma unroll
            for (int q = 0; q < 4; ++q) acc[ci][q] += bv;
        }
    };

    auto store_act = [&](int dst, f32x4* s, bool relu, bool rot) {
        #pragma unroll
        for (int ci = 0; ci < 4; ++ci) {
            int c  = (wu * 4 + ci) * 16 + li;
            int cc = rot ? ((c + 1) & 255) : c;
            #pragma unroll
            for (int q = 0; q < 4; ++q) {
                float v = s[ci][q];
                if (relu) v = fmaxf(v, 0.f);
                f16 hi, lo; fsplit(v, hi, lo);
                Ah[dst][lg * 4 + q][cc] = hi;
                Al[dst][lg * 4 + q][cc] = lo;
            }
        }
    };

    // ---- trunk: 1 barrier per layer ----
    gemm(0, 0, 0, b0);
    #pragma unroll
    for (int ci = 0; ci < 4; ++ci) h[ci] = acc[ci];
    store_act(1, acc, true, false);
    __syncthreads();

    gemm(1, 1, (wu < 3) ? 1 : 0, bb + 0);
    store_act(0, acc, true, false);
    __syncthreads();

    gemm(2, 0, (wu < 3) ? 1 : 0, bb + 256);
    #pragma unroll
    for (int ci = 0; ci < 4; ++ci) h[ci] += acc[ci];
    store_act(1, h, true, false);
    __syncthreads();

    gemm(3, 1, (wu < 3) ? 1 : 0, bb + 512);
    store_act(0, acc, true, false);
    __syncthreads();

    gemm(4, 0, (wu < 3) ? 1 : 0, bb + 768);
    #pragma unroll
    for (int ci = 0; ci < 4; ++ci) h[ci] += acc[ci];
    store_act(1, h, false, true);            // final h: no relu, K-rotated
    __syncthreads();

    // ---- head: wave-private bly, no barriers ----
    float ladreg = 0.f;

    for (int ib = 0; ib < 4; ++ib) {
        const int bly = ib * 4 + wu;
        const int nloop = (bly + 2) >> 1;
        const int f0 = bly * 16;

        #pragma unroll
        for (int pass = 0; pass < 4; ++pass) {
            const int f = f0 + pass * 4 + lg;          // this lane's feature
            const float xv = x[(r0 + li) * 256 + f];   // prefetch (indep of MFMA)

            f32x4 hacc[6];
            #pragma unroll
            for (int ci = 0; ci < 6; ++ci) hacc[ci] = (f32x4){0.f, 0.f, 0.f, 0.f};

            #pragma unroll
            for (int s = 0; s < 8; ++s) {
                if (s < nloop) {                       // wave-uniform
                    f16x8 ah = *(const f16x8*)&Ah[1][li][s * 32 + lg * 8];
                    f16x8 al = *(const f16x8*)&Al[1][li][s * 32 + lg * 8];
                    #pragma unroll
                    for (int ci = 0; ci < 6; ++ci) {
                        f16x8 bv = wh[((bly * 8 + s) * 21 + pass * 5 + ci) * 64 + lane];
                        hacc[ci] = MFMA(al, bv, hacc[ci]);
                        hacc[ci] = MFMA(ah, bv, hacc[ci]);
                    }
                }
            }

            // wave-local fence: previous spline reads of prm[wu] complete
            asm volatile("s_waitcnt lgkmcnt(0)" ::: "memory");

            // scatter C-fragments + bias + scale into private prm
            #pragma unroll
            for (int ci = 0; ci < 6; ++ci) {
                int cl = (pass * 5 + ci) * 16 + li;    // window col = param idx
                int fw = cl / 21;
                int m  = cl - fw * 21;
                if (fw >= pass * 4 && fw < pass * 4 + 4) {
                    float bv = bfp[f0 * 21 + cl];      // coalesced
                    #pragma unroll
                    for (int q = 0; q < 4; ++q)
                        prm[wu][lg * 4 + q][(fw - pass * 4) * 24 + m] =
                            (hacc[ci][q] + bv) * 0.0625f;
                }
            }
            asm volatile("s_waitcnt lgkmcnt(0)" ::: "memory");

            // spline: this lane's (row=li, feature=f)
            float p[21];
            #pragma unroll
            for (int m = 0; m < 21; ++m) p[m] = prm[wu][li][lg * 24 + m];

            float wmax = p[0];
            #pragma unroll
            for (int i = 1; i < 10; ++i) wmax = fmaxf(wmax, p[i]);
            float ew[10]; float wsum = 0.f;
            #pragma unroll
            for (int i = 0; i < 10; ++i) { ew[i] = __expf(p[i] - wmax); wsum += ew[i]; }
            float winv = 1.0f / wsum;
            float wid[10];
            #pragma unroll
            for (int i = 0; i < 10; ++i) wid[i] = 1.0e-3f + 0.99f * ew[i] * winv;

            float hx[11];
            #pragma unroll
            for (int i = 0; i < 11; ++i) hx[i] = __expf(p[10 + i]);
            float area = 0.f;
            #pragma unroll
            for (int i = 0; i < 10; ++i) area += 0.5f * (hx[i] + hx[i + 1]) * wid[i];
            float ainv = 1.0f / area;
            float hts[11];
            #pragma unroll
            for (int i = 0; i < 11; ++i) hts[i] = 1.0e-3f + 0.999f * hx[i] * ainv;

            float cdf[11], locs[11];
            cdf[0] = 0.f; locs[0] = 0.f;
            float ca = 0.f, la = 0.f;
            #pragma unroll
            for (int i = 0; i < 10; ++i) {
                ca += 0.5f * (hts[i] + hts[i + 1]) * wid[i];
                la += wid[i];
                cdf[i + 1] = ca; locs[i + 1] = la;
            }
            cdf[10] = 1.0f; locs[10] = 1.0f;

            int cntk = 0;
            #pragma unroll
            for (int i = 0; i < 11; ++i) cntk += (xv >= locs[i]) ? 1 : 0;
            int idx = cntk - 1;
            idx = idx < 0 ? 0 : (idx > 9 ? 9 : idx);

            float loc = 0.f, ww = 0.f, lc = 0.f, hl = 0.f, hr = 0.f;
            #pragma unroll
            for (int i = 0; i < 10; ++i)
                if (i == idx) { loc = locs[i]; ww = wid[i]; lc = cdf[i]; hl = hts[i]; hr = hts[i + 1]; }

            float aq  = 0.5f * (hr - hl) * ww;
            float bq2 = hl * ww;
            float al2 = (xv - loc) / ww;
            float y = (aq * al2 + bq2) * al2 + lc;
            y = fminf(fmaxf(y, 0.f), 1.f);
            out[(r0 + li) * 256 + f] = y;

            ladreg += __logf(al2 * (hr - hl) + hl);
        }
    }

    // ---- logabsdet: lane-group reduce, then cross-wave via LDS ----
    ladreg += __shfl_xor(ladreg, 16);
    ladreg += __shfl_xor(ladreg, 32);
    if (lane < 16) ladp[wu][lane] = ladreg;
    __syncthreads();
    if (t < 16)
        lad[r0 + t] = ladp[0][t] + ladp[1][t] + ladp[2][t] + ladp[3][t];
}

// ---------------------------------------------------------------------------
extern "C" void kernel_launch(void* const* d_in, const int* in_sizes, int n_in,
                              void* d_out, int out_size, void* d_ws, size_t ws_size,
                              hipStream_t stream)
{
    const float* x  = (const float*)d_in[0];
    const float* W0 = (const float*)d_in[1];
    const float* b0 = (const float*)d_in[2];
    const float* Wb = (const float*)d_in[3];
    const float* bb = (const float*)d_in[4];
    const float* Wf = (const float*)d_in[5];
    const float* bf = (const float*)d_in[6];

    float* out = (float*)d_out;
    float* lad = out + 8192 * 256;
    unsigned char* wsb = (unsigned char*)d_ws;

    prep_kernel<<<832, 256, 0, stream>>>(W0, Wb, Wf, wsb);
    mega_kernel<<<512, 256, 0, stream>>>(x, wsb, b0, bb, bf, out, lad);
}

// Round 5
// 149.557 us; speedup vs baseline: 3.2726x; 1.0843x over previous
//
#include <hip/hip_runtime.h>

typedef _Float16 f16;
typedef f16 f16x8 __attribute__((ext_vector_type(8)));
typedef float f32x4 __attribute__((ext_vector_type(4)));

#define MFMA(A,B,C) __builtin_amdgcn_mfma_f32_16x16x32_f16(A,B,C,0,0,0)

// ws byte offsets (3.4 MB total -> L2-resident)
#define PTRUNK 0u          // 5 mats * 8ks * 16ct * 64lane * 16B = 640 KB
#define PHEAD  655360u     // 16bly * 8ks * 21ct * 64lane * 16B = 2.625 MB

__device__ __forceinline__ void fsplit(float v, f16& hi, f16& lo) {
    hi = (f16)v;
    lo = (f16)(v - (float)hi);
}

// ---------------------------------------------------------------------------
// prep v2: LDS-staged transpose. 416 WGs: b<80 trunk (mat,ct), else head
// (bly,ct). Stage: coalesced k-direction float4 reads of 16 source rows,
// mask (+rotation for head) applied, f16 into sm[16][264]. Write: packed
// b128 fragment stores. Fragment elem e of lane l: k = (l>>4)*8+e,
// col = ct*16+(l&15). Head K ROTATED: pos 0 -> j=255, pos p -> j=p-1.
// ---------------------------------------------------------------------------
__global__ __launch_bounds__(256) void prep_kernel(
    const float* __restrict__ W0, const float* __restrict__ Wb,
    const float* __restrict__ Wf, unsigned char* __restrict__ wsb)
{
    __shared__ f16 sm[16][264];
    const int b = blockIdx.x, t = threadIdx.x;
    const int cr = t >> 4, kc = t & 15;      // stage: row 0..15, k-chunk 0..15

    if (b < 80) {                            // trunk: mat = b>>4, ct = b&15
        const int mat = b >> 4, ct = b & 15;
        const int c = ct * 16 + cr;
        const int cd = c % 255;
        const float* src = ((mat == 0) ? W0 : (Wb + (mat - 1) * 65536)) + c * 256;
        #pragma unroll
        for (int u = 0; u < 4; ++u) {
            const int k = kc * 16 + u * 4;
            float4 v = *(const float4*)(src + k);
            float vv[4] = {v.x, v.y, v.z, v.w};
            #pragma unroll
            for (int e = 0; e < 4; ++e) {
                int kk = k + e;
                int kd = (mat == 0) ? kk : (kk % 255);
                sm[cr][kk] = (cd >= kd) ? (f16)vv[e] : (f16)0.f;
            }
        }
        __syncthreads();
        const int ks = t >> 5, ln = t & 31;
        #pragma unroll
        for (int rep = 0; rep < 2; ++rep) {
            const int L = ln + rep * 32;
            const int li = L & 15, lg = L >> 4;
            f16x8 v = *(const f16x8*)&sm[li][ks * 32 + lg * 8];
            ((f16x8*)(wsb + PTRUNK))[(mat * 128 + ks * 16 + ct) * 64 + L] = v;
        }
    } else {                                 // head: hb = b-80 -> (bly, ct)
        const int hb = b - 80;
        const int bly = hb / 21, ct = hb - bly * 21;
        const int cl = ct * 16 + cr;         // window col 0..335
        const int fw = cl / 21;
        const int f  = bly * 16 + fw;
        const int m  = cl - fw * 21;
        const float* src = Wf + (f * 21 + m) * 256;
        #pragma unroll
        for (int u = 0; u < 4; ++u) {
            const int k = kc * 16 + u * 4;
            float4 v = *(const float4*)(src + k);
            float vv[4] = {v.x, v.y, v.z, v.w};
            #pragma unroll
            for (int e = 0; e < 4; ++e) {
                int kk = k + e;
                int jd = kk % 255;
                sm[cr][(kk + 1) & 255] = (f > jd) ? (f16)vv[e] : (f16)0.f;
            }
        }
        __syncthreads();
        const int ks = t >> 5, ln = t & 31;
        #pragma unroll
        for (int rep = 0; rep < 2; ++rep) {
            const int L = ln + rep * 32;
            const int li = L & 15, lg = L >> 4;
            f16x8 v = *(const f16x8*)&sm[li][ks * 32 + lg * 8];
            ((f16x8*)(wsb + PHEAD))[((bly * 8 + ks) * 21 + ct) * 64 + L] = v;
        }
    }
}

// ---------------------------------------------------------------------------
// mega: trunk (5 masked GEMM layers, 1 barrier each) + barrier-free head.
// 512 WGs x 256 thr, 16 rows/WG. All K-loops are runtime-count (wave-uniform
// scalar) and manually unrolled-by-2 with named double-buffer B prefetch.
// ---------------------------------------------------------------------------
__global__ __launch_bounds__(256, 2) void mega_kernel(
    const float* __restrict__ x, const unsigned char* __restrict__ wsb,
    const float* __restrict__ b0, const float* __restrict__ bb,
    const float* __restrict__ bfp, float* __restrict__ out,
    float* __restrict__ lad)
{
    __shared__ f16  Ah[2][16][280];
    __shared__ f16  Al[2][16][280];
    __shared__ float prm[4][16][100];
    __shared__ float ladp[4][16];

    const int t = threadIdx.x, lane = t & 63;
    const int wu = __builtin_amdgcn_readfirstlane(t >> 6);
    const int li = lane & 15, lg = lane >> 4;
    const int r0 = blockIdx.x * 16;

    // ---- stage x hi/lo ----
    {
        int row = t >> 4, cb = (t & 15) * 16;
        const float* xr = x + (r0 + row) * 256 + cb;
        f16 hi[16], lo[16];
        #pragma unroll
        for (int j = 0; j < 16; j += 4) {
            float4 v4 = *(const float4*)(xr + j);
            fsplit(v4.x, hi[j],     lo[j]);
            fsplit(v4.y, hi[j + 1], lo[j + 1]);
            fsplit(v4.z, hi[j + 2], lo[j + 2]);
            fsplit(v4.w, hi[j + 3], lo[j + 3]);
        }
        *(f16x8*)&Ah[0][row][cb]     = *(f16x8*)&hi[0];
        *(f16x8*)&Ah[0][row][cb + 8] = *(f16x8*)&hi[8];
        *(f16x8*)&Al[0][row][cb]     = *(f16x8*)&lo[0];
        *(f16x8*)&Al[0][row][cb + 8] = *(f16x8*)&lo[8];
    }
    __syncthreads();

    const f16x8* wt = (const f16x8*)(wsb + PTRUNK);
    const f16x8* wh = (const f16x8*)(wsb + PHEAD);

    f32x4 h[4], acc[4];
    const int nkp = 2 * wu + 2;

    auto gemm = [&](int mat, int src, int add7, const float* __restrict__ bias) {
        #pragma unroll
        for (int ci = 0; ci < 4; ++ci) acc[ci] = (f32x4){0.f, 0.f, 0.f, 0.f};
        const int tot = nkp + add7;
        const f16x8* wb = wt + mat * 8192;
        f16x8 bA[4], bB[4];
        #pragma unroll
        for (int ci = 0; ci < 4; ++ci) bA[ci] = wb[(wu * 4 + ci) * 64 + lane];
        for (int s = 0; s < tot; s += 2) {
            const int ks1 = (s + 1 < nkp) ? (s + 1) : 7;
            #pragma unroll
            for (int ci = 0; ci < 4; ++ci)
                bB[ci] = wb[(ks1 * 16 + wu * 4 + ci) * 64 + lane];
            {
                const int ks = (s < nkp) ? s : 7;
                f16x8 ah = *(const f16x8*)&Ah[src][li][ks * 32 + lg * 8];
                f16x8 al = *(const f16x8*)&Al[src][li][ks * 32 + lg * 8];
                #pragma unroll
                for (int ci = 0; ci < 4; ++ci) {
                    acc[ci] = MFMA(al, bA[ci], acc[ci]);
                    acc[ci] = MFMA(ah, bA[ci], acc[ci]);
                }
            }
            const int ks2 = (s + 2 < nkp) ? (s + 2) : 7;
            #pragma unroll
            for (int ci = 0; ci < 4; ++ci)
                bA[ci] = wb[(ks2 * 16 + wu * 4 + ci) * 64 + lane];
            if (s + 1 < tot) {
                f16x8 ah = *(const f16x8*)&Ah[src][li][ks1 * 32 + lg * 8];
                f16x8 al = *(const f16x8*)&Al[src][li][ks1 * 32 + lg * 8];
                #pragma unroll
                for (int ci = 0; ci < 4; ++ci) {
                    acc[ci] = MFMA(al, bB[ci], acc[ci]);
                    acc[ci] = MFMA(ah, bB[ci], acc[ci]);
                }
            }
        }
        #pragma unroll
        for (int ci = 0; ci < 4; ++ci) {
            float bv = bias[(wu * 4 + ci) * 16 + li];
            #pragma unroll
            for (int q = 0; q < 4; ++q) acc[ci][q] += bv;
        }
    };

    auto store_act = [&](int dst, f32x4* s, bool relu, bool rot) {
        #pragma unroll
        for (int ci = 0; ci < 4; ++ci) {
            int c  = (wu * 4 + ci) * 16 + li;
            int cc = rot ? ((c + 1) & 255) : c;
            #pragma unroll
            for (int q = 0; q < 4; ++q) {
                float v = s[ci][q];
                if (relu) v = fmaxf(v, 0.f);
                f16 hi, lo; fsplit(v, hi, lo);
                Ah[dst][lg * 4 + q][cc] = hi;
                Al[dst][lg * 4 + q][cc] = lo;
            }
        }
    };

    // ---- trunk: 1 barrier per layer ----
    gemm(0, 0, 0, b0);
    #pragma unroll
    for (int ci = 0; ci < 4; ++ci) h[ci] = acc[ci];
    store_act(1, acc, true, false);
    __syncthreads();

    gemm(1, 1, (wu < 3) ? 1 : 0, bb + 0);
    store_act(0, acc, true, false);
    __syncthreads();

    gemm(2, 0, (wu < 3) ? 1 : 0, bb + 256);
    #pragma unroll
    for (int ci = 0; ci < 4; ++ci) h[ci] += acc[ci];
    store_act(1, h, true, false);
    __syncthreads();

    gemm(3, 1, (wu < 3) ? 1 : 0, bb + 512);
    store_act(0, acc, true, false);
    __syncthreads();

    gemm(4, 0, (wu < 3) ? 1 : 0, bb + 768);
    #pragma unroll
    for (int ci = 0; ci < 4; ++ci) h[ci] += acc[ci];
    store_act(1, h, false, true);            // final h: no relu, K-rotated
    __syncthreads();

    // ---- head: wave-private bly, no barriers ----
    float ladreg = 0.f;

    for (int ib = 0; ib < 4; ++ib) {
        const int bly = ib * 4 + wu;
        const int nl = (bly + 2) >> 1;       // prefix K-steps (wave-uniform)
        const int f0 = bly * 16;

        #pragma unroll
        for (int pass = 0; pass < 4; ++pass) {
            const int f = f0 + pass * 4 + lg;
            const float xv = x[(r0 + li) * 256 + f];

            f32x4 hacc[6];
            #pragma unroll
            for (int ci = 0; ci < 6; ++ci) hacc[ci] = (f32x4){0.f, 0.f, 0.f, 0.f};

            f16x8 bA[6], bB[6];
            #pragma unroll
            for (int ci = 0; ci < 6; ++ci)
                bA[ci] = wh[((bly * 8) * 21 + pass * 5 + ci) * 64 + lane];

            for (int s = 0; s < nl; s += 2) {
                const int s1 = (s + 1 < nl) ? (s + 1) : (nl - 1);
                #pragma unroll
                for (int ci = 0; ci < 6; ++ci)
                    bB[ci] = wh[((bly * 8 + s1) * 21 + pass * 5 + ci) * 64 + lane];
                {
                    f16x8 ah = *(const f16x8*)&Ah[1][li][s * 32 + lg * 8];
                    f16x8 al = *(const f16x8*)&Al[1][li][s * 32 + lg * 8];
                    #pragma unroll
                    for (int ci = 0; ci < 6; ++ci) {
                        hacc[ci] = MFMA(al, bA[ci], hacc[ci]);
                        hacc[ci] = MFMA(ah, bA[ci], hacc[ci]);
                    }
                }
                const int s2 = (s + 2 < nl) ? (s + 2) : (nl - 1);
                #pragma unroll
                for (int ci = 0; ci < 6; ++ci)
                    bA[ci] = wh[((bly * 8 + s2) * 21 + pass * 5 + ci) * 64 + lane];
                if (s + 1 < nl) {
                    f16x8 ah = *(const f16x8*)&Ah[1][li][s1 * 32 + lg * 8];
                    f16x8 al = *(const f16x8*)&Al[1][li][s1 * 32 + lg * 8];
                    #pragma unroll
                    for (int ci = 0; ci < 6; ++ci) {
                        hacc[ci] = MFMA(al, bB[ci], hacc[ci]);
                        hacc[ci] = MFMA(ah, bB[ci], hacc[ci]);
                    }
                }
            }

            // scatter C-fragments + bias + scale into wave-private prm
            #pragma unroll
            for (int ci = 0; ci < 6; ++ci) {
                int cl = (pass * 5 + ci) * 16 + li;
                int fw = cl / 21;
                int m  = cl - fw * 21;
                if (fw >= pass * 4 && fw < pass * 4 + 4) {
                    float bv = bfp[f0 * 21 + cl];
                    #pragma unroll
                    for (int q = 0; q < 4; ++q)
                        prm[wu][lg * 4 + q][(fw - pass * 4) * 24 + m] =
                            (hacc[ci][q] + bv) * 0.0625f;
                }
            }

            // spline: this lane's (row=li, feature=f)
            float p[21];
            #pragma unroll
            for (int m = 0; m < 21; ++m) p[m] = prm[wu][li][lg * 24 + m];

            float wmax = p[0];
            #pragma unroll
            for (int i = 1; i < 10; ++i) wmax = fmaxf(wmax, p[i]);
            float ew[10]; float wsum = 0.f;
            #pragma unroll
            for (int i = 0; i < 10; ++i) { ew[i] = __expf(p[i] - wmax); wsum += ew[i]; }
            float winv = 1.0f / wsum;
            float wid[10];
            #pragma unroll
            for (int i = 0; i < 10; ++i) wid[i] = 1.0e-3f + 0.99f * ew[i] * winv;

            float hx[11];
            #pragma unroll
            for (int i = 0; i < 11; ++i) hx[i] = __expf(p[10 + i]);
            float area = 0.f;
            #pragma unroll
            for (int i = 0; i < 10; ++i) area += 0.5f * (hx[i] + hx[i + 1]) * wid[i];
            float ainv = 1.0f / area;
            float hts[11];
            #pragma unroll
            for (int i = 0; i < 11; ++i) hts[i] = 1.0e-3f + 0.999f * hx[i] * ainv;

            float cdf[11], locs[11];
            cdf[0] = 0.f; locs[0] = 0.f;
            float ca = 0.f, la = 0.f;
            #pragma unroll
            for (int i = 0; i < 10; ++i) {
                ca += 0.5f * (hts[i] + hts[i + 1]) * wid[i];
                la += wid[i];
                cdf[i + 1] = ca; locs[i + 1] = la;
            }
            cdf[10] = 1.0f; locs[10] = 1.0f;

            int cntk = 0;
            #pragma unroll
            for (int i = 0; i < 11; ++i) cntk += (xv >= locs[i]) ? 1 : 0;
            int idx = cntk - 1;
            idx = idx < 0 ? 0 : (idx > 9 ? 9 : idx);

            float loc = 0.f, ww = 0.f, lc = 0.f, hl = 0.f, hr = 0.f;
            #pragma unroll
            for (int i = 0; i < 10; ++i)
                if (i == idx) { loc = locs[i]; ww = wid[i]; lc = cdf[i]; hl = hts[i]; hr = hts[i + 1]; }

            float aq  = 0.5f * (hr - hl) * ww;
            float bq2 = hl * ww;
            float al2 = (xv - loc) / ww;
            float y = (aq * al2 + bq2) * al2 + lc;
            y = fminf(fmaxf(y, 0.f), 1.f);
            out[(r0 + li) * 256 + f] = y;

            ladreg += __logf(al2 * (hr - hl) + hl);
        }
    }

    // ---- logabsdet reduce ----
    ladreg += __shfl_xor(ladreg, 16);
    ladreg += __shfl_xor(ladreg, 32);
    if (lane < 16) ladp[wu][lane] = ladreg;
    __syncthreads();
    if (t < 16)
        lad[r0 + t] = ladp[0][t] + ladp[1][t] + ladp[2][t] + ladp[3][t];
}

// ---------------------------------------------------------------------------
extern "C" void kernel_launch(void* const* d_in, const int* in_sizes, int n_in,
                              void* d_out, int out_size, void* d_ws, size_t ws_size,
                              hipStream_t stream)
{
    const float* x  = (const float*)d_in[0];
    const float* W0 = (const float*)d_in[1];
    const float* b0 = (const float*)d_in[2];
    const float* Wb = (const float*)d_in[3];
    const float* bb = (const float*)d_in[4];
    const float* Wf = (const float*)d_in[5];
    const float* bf = (const float*)d_in[6];

    float* out = (float*)d_out;
    float* lad = out + 8192 * 256;
    unsigned char* wsb = (unsigned char*)d_ws;

    prep_kernel<<<416, 256, 0, stream>>>(W0, Wb, Wf, wsb);
    mega_kernel<<<512, 256, 0, stream>>>(x, wsb, b0, bb, bf, out, lad);
}

// Round 6
// 136.872 us; speedup vs baseline: 3.5759x; 1.0927x over previous
//
#include <hip/hip_runtime.h>

typedef _Float16 f16;
typedef f16 f16x8 __attribute__((ext_vector_type(8)));
typedef float f32x4 __attribute__((ext_vector_type(4)));

#define MFMA(A,B,C) __builtin_amdgcn_mfma_f32_16x16x32_f16(A,B,C,0,0,0)

// ws byte offsets (3.4 MB total -> L2-resident)
#define PTRUNK 0u          // 5 mats * 8ks * 16ct * 64lane * 16B = 640 KB
#define PHEAD  655360u     // 16bly * 8ks * 21ct * 64lane * 16B = 2.625 MB

// dynamic LDS layout (80384 B total)
//   [0      .. 16896)  Ah1   f16[32][264]
//   [16896  .. 33792)  Al1
//   [33792  .. 50688)  Ah0   (trunk only)   | overlaid: prm f32[128][89] (head)
//   [50688  .. 67584)  Al0   (trunk only)   |           = [33792 .. 79360)
//   [79360  .. 80384)  ladp  f32[8][32]
#define SMEM_BYTES 80384

__device__ __forceinline__ void fsplit(float v, f16& hi, f16& lo) {
    hi = (f16)v;
    lo = (f16)(v - (float)hi);
}

// ---------------------------------------------------------------------------
// prep (unchanged): LDS-staged transpose into MFMA fragment order, fp16.
// Fragment elem e of lane l: k = (l>>4)*8+e, col = ct*16+(l&15).
// Head K ROTATED: pos 0 -> j=255, pos p -> j=p-1 (prefix K-sets).
// ---------------------------------------------------------------------------
__global__ __launch_bounds__(256) void prep_kernel(
    const float* __restrict__ W0, const float* __restrict__ Wb,
    const float* __restrict__ Wf, unsigned char* __restrict__ wsb)
{
    __shared__ f16 sm[16][264];
    const int b = blockIdx.x, t = threadIdx.x;
    const int cr = t >> 4, kc = t & 15;

    if (b < 80) {                            // trunk: mat = b>>4, ct = b&15
        const int mat = b >> 4, ct = b & 15;
        const int c = ct * 16 + cr;
        const int cd = c % 255;
        const float* src = ((mat == 0) ? W0 : (Wb + (mat - 1) * 65536)) + c * 256;
        #pragma unroll
        for (int u = 0; u < 4; ++u) {
            const int k = kc * 16 + u * 4;
            float4 v = *(const float4*)(src + k);
            float vv[4] = {v.x, v.y, v.z, v.w};
            #pragma unroll
            for (int e = 0; e < 4; ++e) {
                int kk = k + e;
                int kd = (mat == 0) ? kk : (kk % 255);
                sm[cr][kk] = (cd >= kd) ? (f16)vv[e] : (f16)0.f;
            }
        }
        __syncthreads();
        const int ks = t >> 5, ln = t & 31;
        #pragma unroll
        for (int rep = 0; rep < 2; ++rep) {
            const int L = ln + rep * 32;
            const int li = L & 15, lg = L >> 4;
            f16x8 v = *(const f16x8*)&sm[li][ks * 32 + lg * 8];
            ((f16x8*)(wsb + PTRUNK))[(mat * 128 + ks * 16 + ct) * 64 + L] = v;
        }
    } else {                                 // head: hb = b-80 -> (bly, ct)
        const int hb = b - 80;
        const int bly = hb / 21, ct = hb - bly * 21;
        const int cl = ct * 16 + cr;
        const int fw = cl / 21;
        const int f  = bly * 16 + fw;
        const int m  = cl - fw * 21;
        const float* src = Wf + (f * 21 + m) * 256;
        #pragma unroll
        for (int u = 0; u < 4; ++u) {
            const int k = kc * 16 + u * 4;
            float4 v = *(const float4*)(src + k);
            float vv[4] = {v.x, v.y, v.z, v.w};
            #pragma unroll
            for (int e = 0; e < 4; ++e) {
                int kk = k + e;
                int jd = kk % 255;
                sm[cr][(kk + 1) & 255] = (f > jd) ? (f16)vv[e] : (f16)0.f;
            }
        }
        __syncthreads();
        const int ks = t >> 5, ln = t & 31;
        #pragma unroll
        for (int rep = 0; rep < 2; ++rep) {
            const int L = ln + rep * 32;
            const int li = L & 15, lg = L >> 4;
            f16x8 v = *(const f16x8*)&sm[li][ks * 32 + lg * 8];
            ((f16x8*)(wsb + PHEAD))[((bly * 8 + ks) * 21 + ct) * 64 + L] = v;
        }
    }
}

// ---------------------------------------------------------------------------
// mega v3: 256 WGs x 512 thr, 32 rows/WG, 8 waves.
// Trunk: wave w owns ct {w, 15-w} (balanced Sum nks = 9), merged K-loop,
// full-register B preload, 2 row-tiles per B-fragment (halved L2 traffic).
// Head: wave w owns bly {w, 15-w} (balanced Sum nl = 9), barrier-free,
// dbuf B prefetch, setprio around MFMA, wave-private prm overlaid on buf0.
// ---------------------------------------------------------------------------
__global__ __launch_bounds__(512, 2) void mega_kernel(
    const float* __restrict__ x, const unsigned char* __restrict__ wsb,
    const float* __restrict__ b0, const float* __restrict__ bb,
    const float* __restrict__ bfp, float* __restrict__ out,
    float* __restrict__ lad)
{
    extern __shared__ unsigned char smem[];
    f16 (*Ah1)[264] = (f16(*)[264])(smem);
    f16 (*Al1)[264] = (f16(*)[264])(smem + 16896);
    f16 (*Ah0)[264] = (f16(*)[264])(smem + 33792);
    f16 (*Al0)[264] = (f16(*)[264])(smem + 50688);
    float* prm      = (float*)(smem + 33792);    // [128][89], head phase only
    float* ladp     = (float*)(smem + 79360);    // [8][32]

    const int t = threadIdx.x, lane = t & 63;
    const int wu = __builtin_amdgcn_readfirstlane(t >> 6);   // wave id 0..7
    const int li = lane & 15, lg = lane >> 4;
    const int r0 = blockIdx.x * 32;

    // ---- stage x hi/lo into buffer 0 ----
    {
        const int row = t >> 4, cb = (t & 15) * 16;
        const float* xr = x + (r0 + row) * 256 + cb;
        f16 hi[16], lo[16];
        #pragma unroll
        for (int j = 0; j < 16; j += 4) {
            float4 v4 = *(const float4*)(xr + j);
            fsplit(v4.x, hi[j],     lo[j]);
            fsplit(v4.y, hi[j + 1], lo[j + 1]);
            fsplit(v4.z, hi[j + 2], lo[j + 2]);
            fsplit(v4.w, hi[j + 3], lo[j + 3]);
        }
        *(f16x8*)&Ah0[row][cb]     = *(f16x8*)&hi[0];
        *(f16x8*)&Ah0[row][cb + 8] = *(f16x8*)&hi[8];
        *(f16x8*)&Al0[row][cb]     = *(f16x8*)&lo[0];
        *(f16x8*)&Al0[row][cb + 8] = *(f16x8*)&lo[8];
    }
    __syncthreads();

    const f16x8* wt = (const f16x8*)(wsb + PTRUNK);
    const f16x8* wh = (const f16x8*)(wsb + PHEAD);

    const int ctA = wu, ctB = 15 - wu;
    const int nkA = (ctA >> 1) + 1;        // 1..4
    const int nkB = (ctB >> 1) + 1;        // 5..8

    f32x4 acc[2][2], h[2][2];

    auto gemm = [&](int mat, f16 (*Sh)[264], f16 (*Sl)[264],
                    const float* __restrict__ bias) {
        const int a7 = (mat > 0) ? 1 : 0;
        const int tB = nkB + ((a7 && nkB < 8) ? 1 : 0);
        const f16x8* wb = wt + mat * 8192;
        f16x8 bfA[9], bfB[9];
        #pragma unroll
        for (int s = 0; s < 9; ++s) {
            if (s < tB) {
                const int ks = (s < nkB) ? s : 7;
                bfB[s] = wb[(ks * 16 + ctB) * 64 + lane];
                if (ks < nkA || (a7 && ks == 7))
                    bfA[s] = wb[(ks * 16 + ctA) * 64 + lane];
            }
        }
        #pragma unroll
        for (int ci = 0; ci < 2; ++ci)
            #pragma unroll
            for (int rt = 0; rt < 2; ++rt)
                acc[ci][rt] = (f32x4){0.f, 0.f, 0.f, 0.f};
        #pragma unroll
        for (int s = 0; s < 9; ++s) {
            if (s < tB) {
                const int ks = (s < nkB) ? s : 7;
                const int ko = ks * 32 + lg * 8;
                f16x8 ah0 = *(const f16x8*)&Sh[li][ko];
                f16x8 al0 = *(const f16x8*)&Sl[li][ko];
                f16x8 ah1 = *(const f16x8*)&Sh[16 + li][ko];
                f16x8 al1 = *(const f16x8*)&Sl[16 + li][ko];
                acc[1][0] = MFMA(al0, bfB[s], acc[1][0]);
                acc[1][0] = MFMA(ah0, bfB[s], acc[1][0]);
                acc[1][1] = MFMA(al1, bfB[s], acc[1][1]);
                acc[1][1] = MFMA(ah1, bfB[s], acc[1][1]);
                if (ks < nkA || (a7 && ks == 7)) {
                    acc[0][0] = MFMA(al0, bfA[s], acc[0][0]);
                    acc[0][0] = MFMA(ah0, bfA[s], acc[0][0]);
                    acc[0][1] = MFMA(al1, bfA[s], acc[0][1]);
                    acc[0][1] = MFMA(ah1, bfA[s], acc[0][1]);
                }
            }
        }
        const float bvA = bias[ctA * 16 + li];
        const float bvB = bias[ctB * 16 + li];
        #pragma unroll
        for (int rt = 0; rt < 2; ++rt)
            #pragma unroll
            for (int q = 0; q < 4; ++q) {
                acc[0][rt][q] += bvA;
                acc[1][rt][q] += bvB;
            }
    };

    auto store_act = [&](f16 (*Dh)[264], f16 (*Dl)[264], f32x4 (&s)[2][2],
                         bool relu, bool rot) {
        #pragma unroll
        for (int ci = 0; ci < 2; ++ci) {
            const int c  = (ci ? ctB : ctA) * 16 + li;
            const int cc = rot ? ((c + 1) & 255) : c;
            #pragma unroll
            for (int rt = 0; rt < 2; ++rt)
                #pragma unroll
                for (int q = 0; q < 4; ++q) {
                    float v = s[ci][rt][q];
                    if (relu) v = fmaxf(v, 0.f);
                    f16 hi, lo; fsplit(v, hi, lo);
                    Dh[rt * 16 + lg * 4 + q][cc] = hi;
                    Dl[rt * 16 + lg * 4 + q][cc] = lo;
                }
        }
    };

    // ---- trunk: 5 layers, 1 barrier each ----
    gemm(0, Ah0, Al0, b0);
    #pragma unroll
    for (int ci = 0; ci < 2; ++ci)
        #pragma unroll
        for (int rt = 0; rt < 2; ++rt) h[ci][rt] = acc[ci][rt];
    store_act(Ah1, Al1, acc, true, false);
    __syncthreads();

    gemm(1, Ah1, Al1, bb);
    store_act(Ah0, Al0, acc, true, false);
    __syncthreads();

    gemm(2, Ah0, Al0, bb + 256);
    #pragma unroll
    for (int ci = 0; ci < 2; ++ci)
        #pragma unroll
        for (int rt = 0; rt < 2; ++rt) h[ci][rt] += acc[ci][rt];
    store_act(Ah1, Al1, h, true, false);
    __syncthreads();

    gemm(3, Ah1, Al1, bb + 512);
    store_act(Ah0, Al0, acc, true, false);
    __syncthreads();

    gemm(4, Ah0, Al0, bb + 768);
    #pragma unroll
    for (int ci = 0; ci < 2; ++ci)
        #pragma unroll
        for (int rt = 0; rt < 2; ++rt) h[ci][rt] += acc[ci][rt];
    store_act(Ah1, Al1, h, false, true);     // final h: no relu, K-rotated
    __syncthreads();                          // buf0 now dead -> prm overlay

    // ---- head: wave-private blys {wu, 15-wu}, barrier-free ----
    float lr0 = 0.f, lr1 = 0.f;

    auto do_half = [&](const f32x4* hacc, int hp, float xv, int pass, int f0,
                       int fme, float& lr) {
        // scatter C-fragments + bias + scale into wave-private prm
        #pragma unroll
        for (int ci = 0; ci < 6; ++ci) {
            const int cl = (pass * 5 + ci) * 16 + li;
            const int fw = cl / 21;
            const int m  = cl - fw * 21;
            if (fw >= pass * 4 && fw < pass * 4 + 4) {
                const float bv = bfp[f0 * 21 + cl];
                #pragma unroll
                for (int q = 0; q < 4; ++q)
                    prm[(wu * 16 + lg * 4 + q) * 89 + (fw - pass * 4) * 22 + m] =
                        (hacc[ci][q] + bv) * 0.0625f;
            }
        }
        // spline: this lane's (row = hp*16+li, feature slot lg)
        float p[21];
        #pragma unroll
        for (int m = 0; m < 21; ++m)
            p[m] = prm[(wu * 16 + li) * 89 + lg * 22 + m];

        float wmax = p[0];
        #pragma unroll
        for (int i = 1; i < 10; ++i) wmax = fmaxf(wmax, p[i]);
        float ew[10]; float wsum = 0.f;
        #pragma unroll
        for (int i = 0; i < 10; ++i) { ew[i] = __expf(p[i] - wmax); wsum += ew[i]; }
        const float winv = 1.0f / wsum;
        float wid[10];
        #pragma unroll
        for (int i = 0; i < 10; ++i) wid[i] = 1.0e-3f + 0.99f * ew[i] * winv;

        float hx[11];
        #pragma unroll
        for (int i = 0; i < 11; ++i) hx[i] = __expf(p[10 + i]);
        float area = 0.f;
        #pragma unroll
        for (int i = 0; i < 10; ++i) area += (hx[i] + hx[i + 1]) * wid[i];
        const float ainv = 2.0f / area;
        float hts[11];
        #pragma unroll
        for (int i = 0; i < 11; ++i) hts[i] = 1.0e-3f + 0.999f * hx[i] * ainv;

        // fused cumsum + searchsorted + gather
        float la = wid[0];
        float ca = 0.5f * (hts[0] + hts[1]) * wid[0];
        float loc = 0.f, ww = wid[0], lc = 0.f, hl = hts[0], hr = hts[1];
        #pragma unroll
        for (int i = 1; i < 10; ++i) {
            const bool sel = (xv >= la);
            loc = sel ? la : loc;
            ww  = sel ? wid[i] : ww;
            lc  = sel ? ca : lc;
            hl  = sel ? hts[i] : hl;
            hr  = sel ? hts[i + 1] : hr;
            la += wid[i];
            ca += 0.5f * (hts[i] + hts[i + 1]) * wid[i];
        }
        const float al2 = (xv - loc) / ww;
        const float dh  = hr - hl;
        float y = (0.5f * dh * ww * al2 + hl * ww) * al2 + lc;
        y = fminf(fmaxf(y, 0.f), 1.f);
        out[(r0 + hp * 16 + li) * 256 + fme] = y;
        lr += __logf(al2 * dh + hl);
    };

    #pragma unroll
    for (int ib = 0; ib < 2; ++ib) {
        const int bly = ib ? (15 - wu) : wu;
        const int nl  = (bly + 2) >> 1;          // 1..8, wave-uniform
        const int f0  = bly * 16;
        const int bly8 = bly * 8;

        #pragma unroll
        for (int pass = 0; pass < 4; ++pass) {
            const int p5  = pass * 5;
            const int fme = f0 + pass * 4 + lg;
            const float xv0 = x[(r0 + li) * 256 + fme];
            const float xv1 = x[(r0 + 16 + li) * 256 + fme];

            f32x4 pA[6], pB[6];
            #pragma unroll
            for (int ci = 0; ci < 6; ++ci) {
                pA[ci] = (f32x4){0.f, 0.f, 0.f, 0.f};
                pB[ci] = (f32x4){0.f, 0.f, 0.f, 0.f};
            }

            f16x8 c0[6], c1[6];
            #pragma unroll
            for (int ci = 0; ci < 6; ++ci)
                c0[ci] = wh[(bly8 * 21 + p5 + ci) * 64 + lane];

            __builtin_amdgcn_s_setprio(1);
            for (int s = 0; s < nl; s += 2) {
                const int s1 = (s + 1 < nl) ? s + 1 : 0;
                #pragma unroll
                for (int ci = 0; ci < 6; ++ci)
                    c1[ci] = wh[((bly8 + s1) * 21 + p5 + ci) * 64 + lane];
                {
                    const int ko = s * 32 + lg * 8;
                    f16x8 ah0 = *(const f16x8*)&Ah1[li][ko];
                    f16x8 al0 = *(const f16x8*)&Al1[li][ko];
                    f16x8 ah1 = *(const f16x8*)&Ah1[16 + li][ko];
                    f16x8 al1 = *(const f16x8*)&Al1[16 + li][ko];
                    #pragma unroll
                    for (int ci = 0; ci < 6; ++ci) {
                        pA[ci] = MFMA(al0, c0[ci], pA[ci]);
                        pA[ci] = MFMA(ah0, c0[ci], pA[ci]);
                        pB[ci] = MFMA(al1, c0[ci], pB[ci]);
                        pB[ci] = MFMA(ah1, c0[ci], pB[ci]);
                    }
                }
                const int s2 = (s + 2 < nl) ? s + 2 : 0;
                #pragma unroll
                for (int ci = 0; ci < 6; ++ci)
                    c0[ci] = wh[((bly8 + s2) * 21 + p5 + ci) * 64 + lane];
                if (s + 1 < nl) {
                    const int ko = s1 * 32 + lg * 8;
                    f16x8 ah0 = *(const f16x8*)&Ah1[li][ko];
                    f16x8 al0 = *(const f16x8*)&Al1[li][ko];
                    f16x8 ah1 = *(const f16x8*)&Ah1[16 + li][ko];
                    f16x8 al1 = *(const f16x8*)&Al1[16 + li][ko];
                    #pragma unroll
                    for (int ci = 0; ci < 6; ++ci) {
                        pA[ci] = MFMA(al0, c1[ci], pA[ci]);
                        pA[ci] = MFMA(ah0, c1[ci], pA[ci]);
                        pB[ci] = MFMA(al1, c1[ci], pB[ci]);
                        pB[ci] = MFMA(ah1, c1[ci], pB[ci]);
                    }
                }
            }
            __builtin_amdgcn_s_setprio(0);

            do_half(pA, 0, xv0, pass, f0, fme, lr0);
            do_half(pB, 1, xv1, pass, f0, fme, lr1);
        }
    }

    // ---- logabsdet: reduce over feature-slots (lg), then waves ----
    lr0 += __shfl_xor(lr0, 16); lr0 += __shfl_xor(lr0, 32);
    lr1 += __shfl_xor(lr1, 16); lr1 += __shfl_xor(lr1, 32);
    if (lane < 16) {
        ladp[wu * 32 + lane]      = lr0;
        ladp[wu * 32 + 16 + lane] = lr1;
    }
    __syncthreads();
    if (t < 32) {
        float s = 0.f;
        #pragma unroll
        for (int w2 = 0; w2 < 8; ++w2) s += ladp[w2 * 32 + t];
        lad[r0 + t] = s;
    }
}

// ---------------------------------------------------------------------------
extern "C" void kernel_launch(void* const* d_in, const int* in_sizes, int n_in,
                              void* d_out, int out_size, void* d_ws, size_t ws_size,
                              hipStream_t stream)
{
    const float* x  = (const float*)d_in[0];
    const float* W0 = (const float*)d_in[1];
    const float* b0 = (const float*)d_in[2];
    const float* Wb = (const float*)d_in[3];
    const float* bb = (const float*)d_in[4];
    const float* Wf = (const float*)d_in[5];
    const float* bf = (const float*)d_in[6];

    float* out = (float*)d_out;
    float* lad = out + 8192 * 256;
    unsigned char* wsb = (unsigned char*)d_ws;

    hipFuncSetAttribute(reinterpret_cast<const void*>(mega_kernel),
                        hipFuncAttributeMaxDynamicSharedMemorySize, SMEM_BYTES);

    prep_kernel<<<416, 256, 0, stream>>>(W0, Wb, Wf, wsb);
    mega_kernel<<<256, 512, SMEM_BYTES, stream>>>(x, wsb, b0, bb, bf, out, lad);
}